// Round 13
// baseline (234.725 us; speedup 1.0000x reference)
//
#include <hip/hip_runtime.h>
#include <hip/hip_bf16.h>

typedef unsigned short u16;
typedef unsigned int u32;
typedef __bf16 bf16;
typedef __attribute__((ext_vector_type(8))) __bf16 bf16x8;
typedef __attribute__((ext_vector_type(4))) __bf16 bf16x4;
typedef __attribute__((ext_vector_type(4))) float f32x4;

#define MFMA16(A,B,C) __builtin_amdgcn_mfma_f32_16x16x32_bf16(A,B,C,0,0,0)

constexpr int NTOK = 49;
constexpr int CH   = 128;
// softmax scale folded into exp2: SCALE * log2(e)
constexpr float CEXP = 0.17677669529663687f * 1.4426950408889634f;

__device__ __forceinline__ bf16x8 lds_v8(const char* p) {
    return *reinterpret_cast<const bf16x8*>(p);
}
__device__ __forceinline__ void lds_st64(char* p, float a0, float a1, float a2, float a3) {
    bf16x4 v = {(bf16)a0, (bf16)a1, (bf16)a2, (bf16)a3};
    *reinterpret_cast<bf16x4*>(p) = v;
}
__device__ __forceinline__ u32 pkbf(float a, float b) {
    u16 lo = __builtin_bit_cast(u16, (bf16)a);
    u16 hi = __builtin_bit_cast(u16, (bf16)b);
    return (u32)lo | ((u32)hi << 16);
}

// D-layout -> A/B-frag layout cross-lane exchange (verified r12).
__device__ __forceinline__ bf16x8 xchg(u32 lo0, u32 lo1, u32 hi0, u32 hi1,
                                       int srcA, int srcB, bool hiT) {
    u32 a0 = __shfl(lo0, srcA), b0 = __shfl(hi0, srcA);
    u32 a1 = __shfl(lo1, srcA), b1 = __shfl(hi1, srcA);
    u32 a2 = __shfl(lo0, srcB), b2 = __shfl(hi0, srcB);
    u32 a3 = __shfl(lo1, srcB), b3 = __shfl(hi1, srcB);
    uint4 u = { hiT ? b0 : a0, hiT ? b1 : a1, hiT ? b2 : a2, hiT ? b3 : a3 };
    return __builtin_bit_cast(bf16x8, u);
}

// Weights fp32 -> bf16, transposed: ws = Wqkv_t[384][128] then Wproj_t[128][128]
__global__ void prep_weights_kernel(const float* __restrict__ wqkv,
                                    const float* __restrict__ wproj,
                                    bf16* __restrict__ ws) {
    int i = blockIdx.x * 256 + threadIdx.x;
    if (i < 384 * 128) {
        int n = i >> 7, k = i & 127;
        ws[i] = (bf16)wqkv[k * 384 + n];
    }
    if (i < 128 * 128) {
        int n = i >> 7, k = i & 127;
        ws[384 * 128 + i] = (bf16)wproj[k * 128 + n];
    }
}

// 8 waves/block: wave w = (head h=w>>1, token-half tf=w&1). Each wave owns
// token rows [tf*32, tf*32+32) of its head's Q/K/V + proj ct tiles {2h,2h+1}
// over its tok-half. Designed for the <=64-reg HW tier (8 waves/SIMD class):
// peak live set ~56-62 regs (xf loaded per-m, chunked softmax).
// LDS = 49,152 B -> 3 blocks/CU = 24 waves/CU (6/SIMD, legal under 8-tier):
//  [0,16384):     Xs [64 tok][128 ch] swz((row&7)<<4); ALIAS (post-B2) O tile
//                 (every wave's xf loads complete before B2).
//  [16384,32768): K slabs Kb(h)=16384+h*4096: [64 tok][32 dh], 64B rows,
//                 swz byte^=((tok&7)<<3). Cross-wave (pair) -> visible at B2.
//  [32768,49152): V slabs Vb(h)=32768+h*4096: [32 dh][64 s], 128B rows,
//                 swz((dh&7)<<4). Cross-wave (pair) -> visible at B2.
// Barriers: B1 stage; B2 {xf consumed block-wide, K/V visible}; B3 O visible.
__launch_bounds__(512, 8)
__global__ void fused_window_attn(const float* __restrict__ x,
                                  const bf16* __restrict__ wqkv_t,
                                  const bf16* __restrict__ wproj_t,
                                  const float* __restrict__ bias,
                                  float* __restrict__ out) {
    __shared__ __align__(16) u16 smem[24576];   // 49,152 B
    char* S8 = reinterpret_cast<char*>(smem);

    const int tid  = threadIdx.x;
    const int blk  = blockIdx.x;
    const int w    = tid >> 6;
    const int h    = w >> 1;      // head
    const int tf   = w & 1;       // token half: tiles {2tf, 2tf+1}
    const int lane = tid & 63;
    const int lr   = lane & 15;
    const int lg   = lane >> 4;
    const int srcA = lr + 32 * (lg & 1);
    const int srcB = srcA + 16;
    const bool hiT = (lg >= 2);

    char* Kb = S8 + 16384 + h * 4096;
    char* Vb = S8 + 32768 + h * 4096;

    // ---------- phase 0: stage x -> Xs (bf16, swizzled); zero pad rows ----------
    const float* xw = x + (size_t)blk * (NTOK * CH);
    #pragma unroll
    for (int it = 0; it < 4; ++it) {
        int i = tid + it * 512;
        if (i < (NTOK * CH) / 4) {
            float4 v = reinterpret_cast<const float4*>(xw)[i];
            int e = i * 4, row = e >> 7, col = e & 127;
            bf16x4 pk4 = { (bf16)v.x, (bf16)v.y, (bf16)v.z, (bf16)v.w };
            *reinterpret_cast<bf16x4*>(S8 + row * 256 + ((col * 2) ^ ((row & 7) << 4))) = pk4;
        }
    }
    if (tid < 240) {  // rows 49..63 exact zeros (whole rows -> swizzle-invariant)
        uint4 zz = {0, 0, 0, 0};
        *reinterpret_cast<uint4*>(S8 + 49 * 256 + tid * 16) = zz;
    }
    __syncthreads();  // B1

    auto wfrag_ld = [&](const bf16* wt, int ct, bf16x8 wf[4]) {
        const bf16* wrow = wt + (ct * 16 + lr) * 128 + lg * 8;
        #pragma unroll
        for (int ks = 0; ks < 4; ++ks)
            wf[ks] = *reinterpret_cast<const bf16x8*>(wrow + ks * 32);
    };

    // ---------- QKV per tok-tile m (xf loaded per-m to cap live regs) ----------
    bf16x8 qf[2];
    #pragma unroll
    for (int m = 0; m < 2; ++m) {
        const int tt = tf * 2 + m;
        bf16x8 xm[4];
        #pragma unroll
        for (int ks = 0; ks < 4; ++ks) {
            int row = tt * 16 + lr;
            xm[ks] = lds_v8(S8 + row * 256 + ((ks * 64 + lg * 16) ^ ((row & 7) << 4)));
        }
        __builtin_amdgcn_s_setprio(1);
        // Q: two dh-halves -> pk -> xchg -> in-register frag
        u32 pkq[2][2];
        #pragma unroll
        for (int half = 0; half < 2; ++half) {
            bf16x8 wf[4];
            wfrag_ld(wqkv_t, 2 * h + half, wf);
            f32x4 a = {0.f, 0.f, 0.f, 0.f};
            #pragma unroll
            for (int ks = 0; ks < 4; ++ks) a = MFMA16(wf[ks], xm[ks], a);
            pkq[half][0] = pkbf(a[0], a[1]);
            pkq[half][1] = pkbf(a[2], a[3]);
        }
        qf[m] = xchg(pkq[0][0], pkq[0][1], pkq[1][0], pkq[1][1], srcA, srcB, hiT);
        // K: two dh-halves -> K slab (cross-wave), packed b64
        #pragma unroll
        for (int half = 0; half < 2; ++half) {
            bf16x8 wf[4];
            wfrag_ld(wqkv_t, 8 + 2 * h + half, wf);
            f32x4 a = {0.f, 0.f, 0.f, 0.f};
            #pragma unroll
            for (int ks = 0; ks < 4; ++ks) a = MFMA16(wf[ks], xm[ks], a);
            int tok = tt * 16 + lr;
            int dh0 = half * 16 + lg * 4;
            lds_st64(Kb + tok * 64 + ((dh0 * 2) ^ ((tok & 7) << 3)),
                     a[0], a[1], a[2], a[3]);
        }
        // V: two dh-halves -> V^T slab (cross-wave), packed b64
        #pragma unroll
        for (int half = 0; half < 2; ++half) {
            bf16x8 wf[4];
            wfrag_ld(wqkv_t, 16 + 2 * h + half, wf);
            f32x4 a = {0.f, 0.f, 0.f, 0.f};
            #pragma unroll
            for (int ks = 0; ks < 4; ++ks) a = MFMA16(xm[ks], wf[ks], a);
            int dh = half * 16 + lr;
            lds_st64(Vb + dh * 128 + ((tt * 32 + lg * 8) ^ ((dh & 7) << 4)),
                     a[0], a[1], a[2], a[3]);
        }
        __builtin_amdgcn_s_setprio(0);
    }
    __syncthreads();  // B2: xf consumed block-wide; K/V slabs complete

    // ---------- K and V fragments from LDS (full 64-token range) ----------
    bf16x8 kf[4];
    #pragma unroll
    for (int st = 0; st < 4; ++st) {
        int tok = st * 16 + lr;
        int o0 = tok * 64 + ((lg * 16) ^ ((tok & 7) << 3));
        bf16x4 klo = *reinterpret_cast<const bf16x4*>(Kb + o0);
        bf16x4 khi = *reinterpret_cast<const bf16x4*>(Kb + (o0 ^ 8));
        bf16x8 k8 = { klo[0],klo[1],klo[2],klo[3], khi[0],khi[1],khi[2],khi[3] };
        kf[st] = k8;
    }
    bf16x8 vf[2][2];
    #pragma unroll
    for (int dht = 0; dht < 2; ++dht)
        #pragma unroll
        for (int ks2 = 0; ks2 < 2; ++ks2) {
            int dh = dht * 16 + lr;
            vf[dht][ks2] = lds_v8(Vb + dh * 128 + ((ks2 * 64 + lg * 16) ^ ((dh & 7) << 4)));
        }

    // ---------- attention per own q-tile (2), chunked softmax, O -> X region ----------
    #pragma unroll
    for (int m = 0; m < 2; ++m) {
        const int qt = tf * 2 + m;
        float l = 0.f;
        u32 pk01[4], pk23[4];
        {   // s-tiles 0,1 (s = 0..31)
            f32x4 s0, s1;
            __builtin_amdgcn_s_setprio(1);
            { f32x4 z = {0,0,0,0}; s0 = MFMA16(kf[0], qf[m], z); }
            { f32x4 z = {0,0,0,0}; s1 = MFMA16(kf[1], qf[m], z); }
            __builtin_amdgcn_s_setprio(0);
            #pragma unroll
            for (int rg = 0; rg < 4; ++rg) {
                float e0 = exp2f(s0[rg] * CEXP);
                float e1 = exp2f(s1[rg] * CEXP);
                s0[rg] = e0; s1[rg] = e1;
                l += e0 + e1;
            }
            pk01[0] = pkbf(s0[0], s0[1]); pk01[1] = pkbf(s0[2], s0[3]);
            pk01[2] = pkbf(s1[0], s1[1]); pk01[3] = pkbf(s1[2], s1[3]);
        }
        {   // s-tiles 2,3 (s = 32..63; only s<=48 valid, st=3 keeps s==48 only)
            f32x4 s2, s3;
            __builtin_amdgcn_s_setprio(1);
            { f32x4 z = {0,0,0,0}; s2 = MFMA16(kf[2], qf[m], z); }
            { f32x4 z = {0,0,0,0}; s3 = MFMA16(kf[3], qf[m], z); }
            __builtin_amdgcn_s_setprio(0);
            #pragma unroll
            for (int rg = 0; rg < 4; ++rg) {
                float e = exp2f(s2[rg] * CEXP);
                s2[rg] = e;
                l += e;
            }
            float e48 = exp2f(s3[0] * CEXP);
            float v48 = (lg == 0) ? e48 : 0.f;
            s3[0] = v48; s3[1] = 0.f; s3[2] = 0.f; s3[3] = 0.f;
            l += v48;
            pk23[0] = pkbf(s2[0], s2[1]); pk23[1] = pkbf(s2[2], s2[3]);
            pk23[2] = pkbf(s3[0], s3[1]); pk23[3] = pkbf(s3[2], s3[3]);
        }
        l += __shfl_xor(l, 16);
        l += __shfl_xor(l, 32);
        float rs = 1.f / l;   // fold normalization into O rescale

        bf16x8 pf0 = xchg(pk01[0], pk01[1], pk01[2], pk01[3], srcA, srcB, hiT);
        bf16x8 pf1 = xchg(pk23[0], pk23[1], pk23[2], pk23[3], srcA, srcB, hiT);

        f32x4 o0 = {0.f, 0.f, 0.f, 0.f}, o1 = {0.f, 0.f, 0.f, 0.f};
        __builtin_amdgcn_s_setprio(1);
        o0 = MFMA16(vf[0][0], pf0, o0);
        o1 = MFMA16(vf[1][0], pf0, o1);
        o0 = MFMA16(vf[0][1], pf1, o0);
        o1 = MFMA16(vf[1][1], pf1, o1);
        __builtin_amdgcn_s_setprio(0);

        // O rows -> X region [tok][ch] (safe: all xf loads were pre-B2)
        int q = qt * 16 + lr;
        lds_st64(S8 + q * 256 + ((h * 64 + lg * 8) ^ ((q & 7) << 4)),
                 o0[0] * rs, o0[1] * rs, o0[2] * rs, o0[3] * rs);
        lds_st64(S8 + q * 256 + ((h * 64 + 32 + lg * 8) ^ ((q & 7) << 4)),
                 o1[0] * rs, o1[1] * rs, o1[2] * rs, o1[3] * rs);
    }
    __syncthreads();  // B3: O tile complete

    // ---------- proj: own ct tiles {2h,2h+1} x own tok tiles ----------
    bf16x8 ofr[2][4];
    #pragma unroll
    for (int m = 0; m < 2; ++m)
        #pragma unroll
        for (int ks = 0; ks < 4; ++ks) {
            int row = (tf * 2 + m) * 16 + lr;
            ofr[m][ks] = lds_v8(S8 + row * 256 + ((ks * 64 + lg * 16) ^ ((row & 7) << 4)));
        }
    #pragma unroll
    for (int i = 0; i < 2; ++i) {
        int ct = 2 * h + i;
        bf16x8 wf[4];
        wfrag_ld(wproj_t, ct, wf);
        float4 bv = *reinterpret_cast<const float4*>(bias + ct * 16 + lg * 4);
        __builtin_amdgcn_s_setprio(1);
        #pragma unroll
        for (int m = 0; m < 2; ++m) {
            f32x4 a = {0.f, 0.f, 0.f, 0.f};
            #pragma unroll
            for (int ks = 0; ks < 4; ++ks) a = MFMA16(wf[ks], ofr[m][ks], a);
            int tok = (tf * 2 + m) * 16 + lr;
            if (tok < NTOK) {
                float4 r = { a[0] + bv.x, a[1] + bv.y, a[2] + bv.z, a[3] + bv.w };
                *reinterpret_cast<float4*>(
                    out + ((size_t)blk * NTOK + tok) * CH + ct * 16 + lg * 4) = r;
            }
        }
        __builtin_amdgcn_s_setprio(0);
    }
}

extern "C" void kernel_launch(void* const* d_in, const int* in_sizes, int n_in,
                              void* d_out, int out_size, void* d_ws, size_t ws_size,
                              hipStream_t stream) {
    const float* x     = (const float*)d_in[0];
    const float* wqkv  = (const float*)d_in[1];
    const float* wproj = (const float*)d_in[2];
    const float* bias  = (const float*)d_in[3];
    float* out = (float*)d_out;
    bf16* ws   = (bf16*)d_ws;

    constexpr size_t WS_NEED = (size_t)(384 * 128 + 128 * 128) * sizeof(u16);
    if (ws_size < WS_NEED) return;

    prep_weights_kernel<<<192, 256, 0, stream>>>(wqkv, wproj, ws);
    fused_window_attn<<<4096, 512, 0, stream>>>(x, ws, ws + 384 * 128, bias, out);
}

// Round 14
// 97.354 us; speedup vs baseline: 2.4110x; 2.4110x over previous
//
#include <hip/hip_runtime.h>
#include <hip/hip_bf16.h>

typedef unsigned short u16;
typedef unsigned int u32;
typedef __bf16 bf16;
typedef __attribute__((ext_vector_type(8))) __bf16 bf16x8;
typedef __attribute__((ext_vector_type(4))) __bf16 bf16x4;
typedef __attribute__((ext_vector_type(4))) float f32x4;

#define MFMA16(A,B,C) __builtin_amdgcn_mfma_f32_16x16x32_bf16(A,B,C,0,0,0)

constexpr int NTOK = 49;
constexpr int CH   = 128;
// softmax scale folded into exp2: SCALE * log2(e)
constexpr float CEXP = 0.17677669529663687f * 1.4426950408889634f;

__device__ __forceinline__ bf16x8 lds_v8(const char* p) {
    return *reinterpret_cast<const bf16x8*>(p);
}
__device__ __forceinline__ void lds_st64(char* p, float a0, float a1, float a2, float a3) {
    bf16x4 v = {(bf16)a0, (bf16)a1, (bf16)a2, (bf16)a3};
    *reinterpret_cast<bf16x4*>(p) = v;
}
__device__ __forceinline__ u32 pkbf(float a, float b) {
    u16 lo = __builtin_bit_cast(u16, (bf16)a);
    u16 hi = __builtin_bit_cast(u16, (bf16)b);
    return (u32)lo | ((u32)hi << 16);
}

// D-layout -> A/B-frag layout cross-lane exchange (verified r12).
__device__ __forceinline__ bf16x8 xchg(u32 lo0, u32 lo1, u32 hi0, u32 hi1,
                                       int srcA, int srcB, bool hiT) {
    u32 a0 = __shfl(lo0, srcA), b0 = __shfl(hi0, srcA);
    u32 a1 = __shfl(lo1, srcA), b1 = __shfl(hi1, srcA);
    u32 a2 = __shfl(lo0, srcB), b2 = __shfl(hi0, srcB);
    u32 a3 = __shfl(lo1, srcB), b3 = __shfl(hi1, srcB);
    uint4 u = { hiT ? b0 : a0, hiT ? b1 : a1, hiT ? b2 : a2, hiT ? b3 : a3 };
    return __builtin_bit_cast(bf16x8, u);
}

// Weights fp32 -> bf16, transposed: ws = Wqkv_t[384][128] then Wproj_t[128][128]
__global__ void prep_weights_kernel(const float* __restrict__ wqkv,
                                    const float* __restrict__ wproj,
                                    bf16* __restrict__ ws) {
    int i = blockIdx.x * 256 + threadIdx.x;
    if (i < 384 * 128) {
        int n = i >> 7, k = i & 127;
        ws[i] = (bf16)wqkv[k * 384 + n];
    }
    if (i < 128 * 128) {
        int n = i >> 7, k = i & 127;
        ws[384 * 128 + i] = (bf16)wproj[k * 128 + n];
    }
}

// 4 waves/block, wave == head, 16x16x32 MFMA, r12 dataflow (Q/K/P in regs via
// xchg, V via own LDS slab) RESTRUCTURED for the 5-blocks/CU register tier:
// xm[4] reloaded from LDS per tok-tile inside each gemm phase (no xf[4][4]
// hold = -48 peak regs); per-phase wf[2][4] held (weight traffic stays 1x —
// r13 lesson: per-m wf reload doubles it). Peak live ~90-95 < 512/5 = 102.
// LDS = 32,768 B -> 5 blocks/CU EXACT (160K/32K):
//  [0,16384):     Xs [64 tok][128 ch] swz((row&7)<<4); ALIAS (post-B3) O tile.
//  [16384,32768): V slabs Vb(h)=16384+h*4096: [32 dh][64 s], 128B rows,
//                 swz((dh&7)<<4). Wave-local (own head) -> no barrier.
// Barriers: B1 (stage), B3 (X reads done block-wide -> O may clobber), B4.
__launch_bounds__(256, 5)
__global__ void fused_window_attn(const float* __restrict__ x,
                                  const bf16* __restrict__ wqkv_t,
                                  const bf16* __restrict__ wproj_t,
                                  const float* __restrict__ bias,
                                  float* __restrict__ out) {
    __shared__ __align__(16) u16 smem[16384];   // 32,768 B
    char* S8 = reinterpret_cast<char*>(smem);

    const int tid  = threadIdx.x;
    const int blk  = blockIdx.x;
    const int h    = tid >> 6;    // wave == head
    const int lane = tid & 63;
    const int lr   = lane & 15;
    const int lg   = lane >> 4;
    const int srcA = lr + 32 * (lg & 1);
    const int srcB = srcA + 16;
    const bool hiT = (lg >= 2);

    char* Vb = S8 + 16384 + h * 4096;

    // ---------- phase 0: stage x -> Xs (bf16, swizzled); zero pad rows ----------
    const float* xw = x + (size_t)blk * (NTOK * CH);
    #pragma unroll
    for (int it = 0; it < 7; ++it) {
        int i = tid + it * 256;
        if (i < (NTOK * CH) / 4) {
            float4 v = reinterpret_cast<const float4*>(xw)[i];
            int e = i * 4, row = e >> 7, col = e & 127;
            bf16x4 pk4 = { (bf16)v.x, (bf16)v.y, (bf16)v.z, (bf16)v.w };
            *reinterpret_cast<bf16x4*>(S8 + row * 256 + ((col * 2) ^ ((row & 7) << 4))) = pk4;
        }
    }
    if (tid < 240) {  // rows 49..63 exact zeros (whole rows -> swizzle-invariant)
        uint4 zz = {0, 0, 0, 0};
        *reinterpret_cast<uint4*>(S8 + 49 * 256 + tid * 16) = zz;
    }
    __syncthreads();  // B1

    // per-tile X fragment reload (A and B fragments share bytes)
    auto xm_ld = [&](int tt, bf16x8 xm[4]) {
        int row = tt * 16 + lr;
        const char* base = S8 + row * 256;
        int xr = (row & 7) << 4;
        #pragma unroll
        for (int ks = 0; ks < 4; ++ks)
            xm[ks] = lds_v8(base + ((ks * 64 + lg * 16) ^ xr));
    };
    auto wf2_ld = [&](const bf16* wt, int ct0, int ct1, bf16x8 wf[2][4]) {
        #pragma unroll
        for (int half = 0; half < 2; ++half) {
            const bf16* wrow = wt + ((half ? ct1 : ct0) * 16 + lr) * 128 + lg * 8;
            #pragma unroll
            for (int ks = 0; ks < 4; ++ks)
                wf[half][ks] = *reinterpret_cast<const bf16x8*>(wrow + ks * 32);
        }
    };

    // ---------- V GEMM -> own LDS slab ----------
    {
        bf16x8 wf[2][4];
        wf2_ld(wqkv_t, 16 + 2 * h, 16 + 2 * h + 1, wf);
        __builtin_amdgcn_s_setprio(1);
        #pragma unroll
        for (int tt = 0; tt < 4; ++tt) {
            bf16x8 xm[4];
            xm_ld(tt, xm);
            #pragma unroll
            for (int i = 0; i < 2; ++i) {
                f32x4 a = {0.f, 0.f, 0.f, 0.f};
                #pragma unroll
                for (int ks = 0; ks < 4; ++ks) a = MFMA16(xm[ks], wf[i][ks], a);
                int dh = i * 16 + lr;
                lds_st64(Vb + dh * 128 + ((tt * 32 + lg * 8) ^ ((dh & 7) << 4)),
                         a[0], a[1], a[2], a[3]);
            }
        }
        __builtin_amdgcn_s_setprio(0);
    }

    // ---------- Q GEMM -> in-register frags via xchg ----------
    bf16x8 qf[4];
    {
        bf16x8 wf[2][4];
        wf2_ld(wqkv_t, 2 * h, 2 * h + 1, wf);
        u32 pkq[4][2][2];   // [tt][half][pair]
        __builtin_amdgcn_s_setprio(1);
        #pragma unroll
        for (int tt = 0; tt < 4; ++tt) {
            bf16x8 xm[4];
            xm_ld(tt, xm);
            #pragma unroll
            for (int half = 0; half < 2; ++half) {
                f32x4 a = {0.f, 0.f, 0.f, 0.f};
                #pragma unroll
                for (int ks = 0; ks < 4; ++ks) a = MFMA16(wf[half][ks], xm[ks], a);
                pkq[tt][half][0] = pkbf(a[0], a[1]);
                pkq[tt][half][1] = pkbf(a[2], a[3]);
            }
        }
        __builtin_amdgcn_s_setprio(0);
        #pragma unroll
        for (int tt = 0; tt < 4; ++tt)
            qf[tt] = xchg(pkq[tt][0][0], pkq[tt][0][1],
                          pkq[tt][1][0], pkq[tt][1][1], srcA, srcB, hiT);
    }
    // ---------- K GEMM -> in-register frags via xchg ----------
    bf16x8 kf[4];
    {
        bf16x8 wf[2][4];
        wf2_ld(wqkv_t, 8 + 2 * h, 8 + 2 * h + 1, wf);
        u32 pkk[4][2][2];
        __builtin_amdgcn_s_setprio(1);
        #pragma unroll
        for (int tt = 0; tt < 4; ++tt) {
            bf16x8 xm[4];
            xm_ld(tt, xm);
            #pragma unroll
            for (int half = 0; half < 2; ++half) {
                f32x4 a = {0.f, 0.f, 0.f, 0.f};
                #pragma unroll
                for (int ks = 0; ks < 4; ++ks) a = MFMA16(wf[half][ks], xm[ks], a);
                pkk[tt][half][0] = pkbf(a[0], a[1]);
                pkk[tt][half][1] = pkbf(a[2], a[3]);
            }
        }
        __builtin_amdgcn_s_setprio(0);
        #pragma unroll
        for (int tt = 0; tt < 4; ++tt)
            kf[tt] = xchg(pkk[tt][0][0], pkk[tt][0][1],
                          pkk[tt][1][0], pkk[tt][1][1], srcA, srcB, hiT);
    }

    // V fragments (own slab; wave-local RAW, no barrier needed)
    bf16x8 vf[2][2];
    #pragma unroll
    for (int dht = 0; dht < 2; ++dht)
        #pragma unroll
        for (int ks2 = 0; ks2 < 2; ++ks2) {
            int dh = dht * 16 + lr;
            vf[dht][ks2] = lds_v8(Vb + dh * 128 + ((ks2 * 64 + lg * 16) ^ ((dh & 7) << 4)));
        }
    __syncthreads();  // B3: all waves past X reads; O may now clobber X region

    // ---------- per-qt: S^T = K @ Q^T, no-max softmax, pf via xchg, PV, O ----------
    #pragma unroll
    for (int qt = 0; qt < 4; ++qt) {
        f32x4 s[4];
        __builtin_amdgcn_s_setprio(1);
        #pragma unroll
        for (int st = 0; st < 4; ++st) {
            f32x4 z = {0.f, 0.f, 0.f, 0.f};
            s[st] = MFMA16(kf[st], qf[qt], z);  // lane col = q, regs = s rows
        }
        __builtin_amdgcn_s_setprio(0);
        // no-max softmax (S~N(0,1), |S|max~6 -> exp2 safe); mask pad s>=49
        float l = 0.f;
        #pragma unroll
        for (int st = 0; st < 3; ++st)
            #pragma unroll
            for (int rg = 0; rg < 4; ++rg) {
                float e = exp2f(s[st][rg] * CEXP);
                s[st][rg] = e;
                l += e;
            }
        {   // st=3: s = 48 + 4*lg + rg; only s==48 (lg==0,rg==0) valid
            float e48 = exp2f(s[3][0] * CEXP);
            float v48 = (lg == 0) ? e48 : 0.f;
            s[3][0] = v48; s[3][1] = 0.f; s[3][2] = 0.f; s[3][3] = 0.f;
            l += v48;
        }
        l += __shfl_xor(l, 16);
        l += __shfl_xor(l, 32);
        float rs = 1.f / l;   // fold normalization into O rescale

        // P -> B-frags in-register
        u32 pks[4][2];
        #pragma unroll
        for (int st = 0; st < 4; ++st) {
            pks[st][0] = pkbf(s[st][0], s[st][1]);
            pks[st][1] = pkbf(s[st][2], s[st][3]);
        }
        bf16x8 pf0 = xchg(pks[0][0], pks[0][1], pks[1][0], pks[1][1], srcA, srcB, hiT);
        bf16x8 pf1 = xchg(pks[2][0], pks[2][1], pks[3][0], pks[3][1], srcA, srcB, hiT);

        // O^T = V^T @ P^T for this qt: lane col = q, regs = 4 consecutive dh
        f32x4 o0 = {0.f, 0.f, 0.f, 0.f}, o1 = {0.f, 0.f, 0.f, 0.f};
        __builtin_amdgcn_s_setprio(1);
        o0 = MFMA16(vf[0][0], pf0, o0);
        o1 = MFMA16(vf[1][0], pf0, o1);
        o0 = MFMA16(vf[0][1], pf1, o0);
        o1 = MFMA16(vf[1][1], pf1, o1);
        __builtin_amdgcn_s_setprio(0);

        // O rows -> X region [tok][ch], packed b64, rescaled
        int q = qt * 16 + lr;
        lds_st64(S8 + q * 256 + ((h * 64 + lg * 8) ^ ((q & 7) << 4)),
                 o0[0] * rs, o0[1] * rs, o0[2] * rs, o0[3] * rs);
        lds_st64(S8 + q * 256 + ((h * 64 + 32 + lg * 8) ^ ((q & 7) << 4)),
                 o1[0] * rs, o1[1] * rs, o1[2] * rs, o1[3] * rs);
    }
    __syncthreads();  // B4

    // ---------- proj GEMM + bias -> float4 out (per-tile om reload) ----------
    {
        bf16x8 wf[2][4];
        wf2_ld(wproj_t, 2 * h, 2 * h + 1, wf);
        float4 bv0 = *reinterpret_cast<const float4*>(bias + (2 * h) * 16 + lg * 4);
        float4 bv1 = *reinterpret_cast<const float4*>(bias + (2 * h + 1) * 16 + lg * 4);
        #pragma unroll
        for (int tt = 0; tt < 4; ++tt) {
            bf16x8 om[4];
            xm_ld(tt, om);
            int tok = tt * 16 + lr;
            __builtin_amdgcn_s_setprio(1);
            #pragma unroll
            for (int i = 0; i < 2; ++i) {
                f32x4 a = {0.f, 0.f, 0.f, 0.f};
                #pragma unroll
                for (int ks = 0; ks < 4; ++ks) a = MFMA16(wf[i][ks], om[ks], a);
                if (tok < NTOK) {
                    float4 bv = i ? bv1 : bv0;
                    float4 r = { a[0] + bv.x, a[1] + bv.y, a[2] + bv.z, a[3] + bv.w };
                    *reinterpret_cast<float4*>(
                        out + ((size_t)blk * NTOK + tok) * CH + (2 * h + i) * 16 + lg * 4) = r;
                }
            }
            __builtin_amdgcn_s_setprio(0);
        }
    }
}

extern "C" void kernel_launch(void* const* d_in, const int* in_sizes, int n_in,
                              void* d_out, int out_size, void* d_ws, size_t ws_size,
                              hipStream_t stream) {
    const float* x     = (const float*)d_in[0];
    const float* wqkv  = (const float*)d_in[1];
    const float* wproj = (const float*)d_in[2];
    const float* bias  = (const float*)d_in[3];
    float* out = (float*)d_out;
    bf16* ws   = (bf16*)d_ws;

    constexpr size_t WS_NEED = (size_t)(384 * 128 + 128 * 128) * sizeof(u16);
    if (ws_size < WS_NEED) return;

    prep_weights_kernel<<<192, 256, 0, stream>>>(wqkv, wproj, ws);
    fused_window_attn<<<4096, 256, 0, stream>>>(x, ws, ws + 384 * 128, bias, out);
}

// Round 15
// 89.588 us; speedup vs baseline: 2.6201x; 1.0867x over previous
//
#include <hip/hip_runtime.h>
#include <hip/hip_bf16.h>

typedef unsigned short u16;
typedef unsigned int u32;
typedef __bf16 bf16;
typedef __attribute__((ext_vector_type(8))) __bf16 bf16x8;
typedef __attribute__((ext_vector_type(4))) __bf16 bf16x4;
typedef __attribute__((ext_vector_type(4))) float f32x4;

#define MFMA16(A,B,C) __builtin_amdgcn_mfma_f32_16x16x32_bf16(A,B,C,0,0,0)

constexpr int NTOK = 49;
constexpr int CH   = 128;
// softmax scale folded into exp2: SCALE * log2(e)
constexpr float CEXP = 0.17677669529663687f * 1.4426950408889634f;

__device__ __forceinline__ bf16x8 lds_v8(const char* p) {
    return *reinterpret_cast<const bf16x8*>(p);
}
__device__ __forceinline__ void lds_st64(char* p, float a0, float a1, float a2, float a3) {
    bf16x4 v = {(bf16)a0, (bf16)a1, (bf16)a2, (bf16)a3};
    *reinterpret_cast<bf16x4*>(p) = v;
}
__device__ __forceinline__ u32 pkbf(float a, float b) {
    u16 lo = __builtin_bit_cast(u16, (bf16)a);
    u16 hi = __builtin_bit_cast(u16, (bf16)b);
    return (u32)lo | ((u32)hi << 16);
}

// D-layout -> A/B-frag layout cross-lane exchange (verified r12).
__device__ __forceinline__ bf16x8 xchg(u32 lo0, u32 lo1, u32 hi0, u32 hi1,
                                       int srcA, int srcB, bool hiT) {
    u32 a0 = __shfl(lo0, srcA), b0 = __shfl(hi0, srcA);
    u32 a1 = __shfl(lo1, srcA), b1 = __shfl(hi1, srcA);
    u32 a2 = __shfl(lo0, srcB), b2 = __shfl(hi0, srcB);
    u32 a3 = __shfl(lo1, srcB), b3 = __shfl(hi1, srcB);
    uint4 u = { hiT ? b0 : a0, hiT ? b1 : a1, hiT ? b2 : a2, hiT ? b3 : a3 };
    return __builtin_bit_cast(bf16x8, u);
}

// Weights fp32 -> bf16, transposed: ws = Wqkv_t[384][128] then Wproj_t[128][128]
__global__ void prep_weights_kernel(const float* __restrict__ wqkv,
                                    const float* __restrict__ wproj,
                                    bf16* __restrict__ ws) {
    int i = blockIdx.x * 256 + threadIdx.x;
    if (i < 384 * 128) {
        int n = i >> 7, k = i & 127;
        ws[i] = (bf16)wqkv[k * 384 + n];
    }
    if (i < 128 * 128) {
        int n = i >> 7, k = i & 127;
        ws[384 * 128 + i] = (bf16)wproj[k * 128 + n];
    }
}

// r12 structure (best: 91.8 us) + two latency cuts:
//  (1) row-sum l via MFMA(ones, pf) on the matrix pipe instead of the serial
//      2x shfl_xor chain (240cy x 4qt on the critical path). Normalizing by
//      the bf16-rounded P sum is self-consistent with the bf16 PV product.
//  (2) V-phase weight fragments loaded BEFORE B1 (issue under the stage-wait).
// 4 waves/block, wave == head, 16x16x32 MFMA. Q/K/P in REGISTERS via xchg.
// LDS = 32,768 B -> (256,4): 4 blocks/CU (r5-r14: the only good tier here).
//  [0,16384):     Xs [64 tok][128 ch] swz((row&7)<<4); ALIAS (post-B3) O tile.
//  [16384,32768): V slabs Vb(h)=16384+h*4096: [32 dh][64 s], 128B rows,
//                 swz((dh&7)<<4). Wave-local -> no barrier.
// Barriers: B1 (stage), B3 (X reads done block-wide), B4 (O tile ready).
__launch_bounds__(256, 4)
__global__ void fused_window_attn(const float* __restrict__ x,
                                  const bf16* __restrict__ wqkv_t,
                                  const bf16* __restrict__ wproj_t,
                                  const float* __restrict__ bias,
                                  float* __restrict__ out) {
    __shared__ __align__(16) u16 smem[16384];   // 32,768 B
    char* S8 = reinterpret_cast<char*>(smem);

    const int tid  = threadIdx.x;
    const int blk  = blockIdx.x;
    const int h    = tid >> 6;    // wave == head
    const int lane = tid & 63;
    const int lr   = lane & 15;
    const int lg   = lane >> 4;
    const int srcA = lr + 32 * (lg & 1);
    const int srcB = srcA + 16;
    const bool hiT = (lg >= 2);

    char* Vb = S8 + 16384 + h * 4096;

    // ---------- phase 0: stage x -> Xs (bf16, swizzled); zero pad rows ----------
    const float* xw = x + (size_t)blk * (NTOK * CH);
    #pragma unroll
    for (int it = 0; it < 7; ++it) {
        int i = tid + it * 256;
        if (i < (NTOK * CH) / 4) {
            float4 v = reinterpret_cast<const float4*>(xw)[i];
            int e = i * 4, row = e >> 7, col = e & 127;
            bf16x4 pk4 = { (bf16)v.x, (bf16)v.y, (bf16)v.z, (bf16)v.w };
            *reinterpret_cast<bf16x4*>(S8 + row * 256 + ((col * 2) ^ ((row & 7) << 4))) = pk4;
        }
    }
    if (tid < 240) {  // rows 49..63 exact zeros (whole rows -> swizzle-invariant)
        uint4 zz = {0, 0, 0, 0};
        *reinterpret_cast<uint4*>(S8 + 49 * 256 + tid * 16) = zz;
    }

    // V-phase weight frags: issue BEFORE the barrier (independent global loads
    // overlap the stage drain).
    bf16x8 wfv[2][4];
    #pragma unroll
    for (int half = 0; half < 2; ++half) {
        const bf16* wrow = wqkv_t + ((16 + 2 * h + half) * 16 + lr) * 128 + lg * 8;
        #pragma unroll
        for (int ks = 0; ks < 4; ++ks)
            wfv[half][ks] = *reinterpret_cast<const bf16x8*>(wrow + ks * 32);
    }
    __syncthreads();  // B1

    // ---------- X -> registers (A and B fragments share bytes) ----------
    bf16x8 xf[4][4];  // [tok-tile][kstep]
    #pragma unroll
    for (int tt = 0; tt < 4; ++tt)
        #pragma unroll
        for (int ks = 0; ks < 4; ++ks) {
            int row = tt * 16 + lr;
            xf[tt][ks] = lds_v8(S8 + row * 256 + ((ks * 64 + lg * 16) ^ ((row & 7) << 4)));
        }

    __builtin_amdgcn_s_setprio(1);
    // ---------- V GEMM first (results to LDS slab, no held frags) ----------
    #pragma unroll
    for (int i = 0; i < 2; ++i) {
        int dh = i * 16 + lr;
        #pragma unroll
        for (int tt = 0; tt < 4; ++tt) {
            f32x4 a = {0.f, 0.f, 0.f, 0.f};
            #pragma unroll
            for (int ks = 0; ks < 4; ++ks) a = MFMA16(xf[tt][ks], wfv[i][ks], a);
            lds_st64(Vb + dh * 128 + ((tt * 32 + lg * 8) ^ ((dh & 7) << 4)),
                     a[0], a[1], a[2], a[3]);
        }
    }

    // ---------- Q GEMM -> in-register frags via xchg ----------
    bf16x8 qf[4];
    {
        u32 pkq[2][4][2];
        #pragma unroll
        for (int half = 0; half < 2; ++half) {
            int ct = 2 * h + half;
            bf16x8 wf[4];
            const bf16* wrow = wqkv_t + (ct * 16 + lr) * 128 + lg * 8;
            #pragma unroll
            for (int ks = 0; ks < 4; ++ks)
                wf[ks] = *reinterpret_cast<const bf16x8*>(wrow + ks * 32);
            #pragma unroll
            for (int tt = 0; tt < 4; ++tt) {
                f32x4 a = {0.f, 0.f, 0.f, 0.f};
                #pragma unroll
                for (int ks = 0; ks < 4; ++ks) a = MFMA16(wf[ks], xf[tt][ks], a);
                pkq[half][tt][0] = pkbf(a[0], a[1]);
                pkq[half][tt][1] = pkbf(a[2], a[3]);
            }
        }
        #pragma unroll
        for (int tt = 0; tt < 4; ++tt)
            qf[tt] = xchg(pkq[0][tt][0], pkq[0][tt][1],
                          pkq[1][tt][0], pkq[1][tt][1], srcA, srcB, hiT);
    }
    // ---------- K GEMM -> in-register frags via xchg ----------
    bf16x8 kf[4];
    {
        u32 pkk[2][4][2];
        #pragma unroll
        for (int half = 0; half < 2; ++half) {
            int ct = 8 + 2 * h + half;
            bf16x8 wf[4];
            const bf16* wrow = wqkv_t + (ct * 16 + lr) * 128 + lg * 8;
            #pragma unroll
            for (int ks = 0; ks < 4; ++ks)
                wf[ks] = *reinterpret_cast<const bf16x8*>(wrow + ks * 32);
            #pragma unroll
            for (int tt = 0; tt < 4; ++tt) {
                f32x4 a = {0.f, 0.f, 0.f, 0.f};
                #pragma unroll
                for (int ks = 0; ks < 4; ++ks) a = MFMA16(wf[ks], xf[tt][ks], a);
                pkk[half][tt][0] = pkbf(a[0], a[1]);
                pkk[half][tt][1] = pkbf(a[2], a[3]);
            }
        }
        #pragma unroll
        for (int tt = 0; tt < 4; ++tt)
            kf[tt] = xchg(pkk[0][tt][0], pkk[0][tt][1],
                          pkk[1][tt][0], pkk[1][tt][1], srcA, srcB, hiT);
    }
    __builtin_amdgcn_s_setprio(0);

    // V fragments (own slab; wave-local RAW, no barrier needed)
    bf16x8 vf[2][2];
    #pragma unroll
    for (int dht = 0; dht < 2; ++dht)
        #pragma unroll
        for (int ks2 = 0; ks2 < 2; ++ks2) {
            int dh = dht * 16 + lr;
            vf[dht][ks2] = lds_v8(Vb + dh * 128 + ((ks2 * 64 + lg * 16) ^ ((dh & 7) << 4)));
        }
    __syncthreads();  // B3: all waves past xf loads; O may now clobber X region

    // ones A-fragment for the MFMA row-sum
    bf16x8 ones;
    #pragma unroll
    for (int j = 0; j < 8; ++j) ones[j] = (bf16)1.0f;

    // ---------- per-qt: S^T = K @ Q^T, no-max softmax, pf via xchg, PV, O ----------
    #pragma unroll
    for (int qt = 0; qt < 4; ++qt) {
        f32x4 s[4];
        __builtin_amdgcn_s_setprio(1);
        #pragma unroll
        for (int st = 0; st < 4; ++st) {
            f32x4 z = {0.f, 0.f, 0.f, 0.f};
            s[st] = MFMA16(kf[st], qf[qt], z);  // lane col = q, regs = s rows
        }
        __builtin_amdgcn_s_setprio(0);
        // no-max softmax (S~N(0,1), |S|max~6 -> exp2 safe); mask pad s>=49
        #pragma unroll
        for (int st = 0; st < 3; ++st)
            #pragma unroll
            for (int rg = 0; rg < 4; ++rg)
                s[st][rg] = exp2f(s[st][rg] * CEXP);
        {   // st=3: s = 48 + 4*lg + rg; only s==48 (lg==0,rg==0) valid
            float e48 = exp2f(s[3][0] * CEXP);
            s[3][0] = (lg == 0) ? e48 : 0.f;
            s[3][1] = 0.f; s[3][2] = 0.f; s[3][3] = 0.f;
        }

        // P -> B-frags in-register
        u32 pks[4][2];
        #pragma unroll
        for (int st = 0; st < 4; ++st) {
            pks[st][0] = pkbf(s[st][0], s[st][1]);
            pks[st][1] = pkbf(s[st][2], s[st][3]);
        }
        bf16x8 pf0 = xchg(pks[0][0], pks[0][1], pks[1][0], pks[1][1], srcA, srcB, hiT);
        bf16x8 pf1 = xchg(pks[2][0], pks[2][1], pks[3][0], pks[3][1], srcA, srcB, hiT);

        // row-sum on the MFMA pipe: l[q] = sum_s P[s][q] (pad cols are exact 0;
        // bf16-P sum is self-consistent with the bf16 PV product below)
        __builtin_amdgcn_s_setprio(1);
        f32x4 lacc = {0.f, 0.f, 0.f, 0.f};
        lacc = MFMA16(ones, pf0, lacc);
        lacc = MFMA16(ones, pf1, lacc);

        // O^T = V^T @ P^T for this qt: lane col = q, regs = 4 consecutive dh
        f32x4 o0 = {0.f, 0.f, 0.f, 0.f}, o1 = {0.f, 0.f, 0.f, 0.f};
        o0 = MFMA16(vf[0][0], pf0, o0);
        o1 = MFMA16(vf[1][0], pf0, o1);
        o0 = MFMA16(vf[0][1], pf1, o0);
        o1 = MFMA16(vf[1][1], pf1, o1);
        __builtin_amdgcn_s_setprio(0);
        float rs = 1.f / lacc[0];   // every reg of lacc holds the same sum

        // O rows -> X region [tok][ch], packed b64, rescaled
        int q = qt * 16 + lr;
        lds_st64(S8 + q * 256 + ((h * 64 + lg * 8) ^ ((q & 7) << 4)),
                 o0[0] * rs, o0[1] * rs, o0[2] * rs, o0[3] * rs);
        lds_st64(S8 + q * 256 + ((h * 64 + 32 + lg * 8) ^ ((q & 7) << 4)),
                 o1[0] * rs, o1[1] * rs, o1[2] * rs, o1[3] * rs);
    }
    __syncthreads();  // B4

    // ---------- proj GEMM + bias -> float4 out ----------
    bf16x8 ofr[4][4];
    #pragma unroll
    for (int tt = 0; tt < 4; ++tt)
        #pragma unroll
        for (int ks = 0; ks < 4; ++ks) {
            int row = tt * 16 + lr;
            ofr[tt][ks] = lds_v8(S8 + row * 256 + ((ks * 64 + lg * 16) ^ ((row & 7) << 4)));
        }
    #pragma unroll
    for (int i = 0; i < 2; ++i) {
        int ct = 2 * h + i;
        bf16x8 wf[4];
        const bf16* wrow = wproj_t + (ct * 16 + lr) * 128 + lg * 8;
        #pragma unroll
        for (int ks = 0; ks < 4; ++ks)
            wf[ks] = *reinterpret_cast<const bf16x8*>(wrow + ks * 32);
        float4 bv = *reinterpret_cast<const float4*>(bias + ct * 16 + lg * 4);
        __builtin_amdgcn_s_setprio(1);
        #pragma unroll
        for (int tt = 0; tt < 4; ++tt) {
            f32x4 a = {0.f, 0.f, 0.f, 0.f};
            #pragma unroll
            for (int ks = 0; ks < 4; ++ks) a = MFMA16(wf[ks], ofr[tt][ks], a);
            int tok = tt * 16 + lr;
            if (tok < NTOK) {
                float4 r = { a[0] + bv.x, a[1] + bv.y, a[2] + bv.z, a[3] + bv.w };
                *reinterpret_cast<float4*>(
                    out + ((size_t)blk * NTOK + tok) * CH + ct * 16 + lg * 4) = r;
            }
        }
        __builtin_amdgcn_s_setprio(0);
    }
}

extern "C" void kernel_launch(void* const* d_in, const int* in_sizes, int n_in,
                              void* d_out, int out_size, void* d_ws, size_t ws_size,
                              hipStream_t stream) {
    const float* x     = (const float*)d_in[0];
    const float* wqkv  = (const float*)d_in[1];
    const float* wproj = (const float*)d_in[2];
    const float* bias  = (const float*)d_in[3];
    float* out = (float*)d_out;
    bf16* ws   = (bf16*)d_ws;

    constexpr size_t WS_NEED = (size_t)(384 * 128 + 128 * 128) * sizeof(u16);
    if (ws_size < WS_NEED) return;

    prep_weights_kernel<<<192, 256, 0, stream>>>(wqkv, wproj, ws);
    fused_window_attn<<<4096, 256, 0, stream>>>(x, ws, ws + 384 * 128, bias, out);
}